// Round 12
// baseline (264.878 us; speedup 1.0000x reference)
//
#include <hip/hip_runtime.h>
#include <stdint.h>

// TransformerBlock: x:[1,4096,1024] f32 -> out f32
// DIM=1024 NH=16 HD=64 HIDDEN=2816 SEQ=4096 eps=1e-5
// bf16 MFMA GEMMs (BK=32, 2-phase dbuf, __launch_bounds__(256,4) for 4 blocks/CU)
// + flash attention (flash-decoding split, fixed-max softmax, bf16 partials).

typedef unsigned short u16;
typedef unsigned int u32;
typedef __attribute__((ext_vector_type(8))) short short8;   // 8 x bf16 (4 VGPR)
typedef __attribute__((ext_vector_type(4))) float f32x4;

#define GLD16(G, L) __builtin_amdgcn_global_load_lds( \
    (__attribute__((address_space(1))) void*)(G),      \
    (__attribute__((address_space(3))) void*)(L), 16, 0, 0)

__device__ __forceinline__ u16 f2bf(float f) {  // RNE
  u32 u = __builtin_bit_cast(u32, f);
  u32 r = u + 0x7fffu + ((u >> 16) & 1u);
  return (u16)(r >> 16);
}
__device__ __forceinline__ float bf2f(u16 b) {
  u32 u = (u32)b << 16;
  return __builtin_bit_cast(float, u);
}
__device__ __forceinline__ u32 pk_bf16(float lo, float hi) {  // T12
  u32 r;
  asm("v_cvt_pk_bf16_f32 %0, %1, %2" : "=v"(r) : "v"(lo), "v"(hi));
  return r;
}

// ---------- transpose + convert: in[R][C] f32 -> out[C][R] bf16, z-muxed ----------
__global__ __launch_bounds__(256) void k_tc4(const float* __restrict__ s0,
                                             const float* __restrict__ s1,
                                             const float* __restrict__ s2,
                                             const float* __restrict__ s3,
                                             u16* __restrict__ out, int R, int C) {
  const int z = blockIdx.z;
  const float* in = (z == 0) ? s0 : (z == 1) ? s1 : (z == 2) ? s2 : s3;
  u16* o = out + (size_t)z * R * C;
  __shared__ float t[32][33];
  const int tx = threadIdx.x & 31, ty = threadIdx.x >> 5;
  const int c0 = blockIdx.x * 32, r0 = blockIdx.y * 32;
#pragma unroll
  for (int i = 0; i < 32; i += 8)
    t[ty + i][tx] = in[(size_t)(r0 + ty + i) * C + (c0 + tx)];
  __syncthreads();
#pragma unroll
  for (int i = 0; i < 32; i += 8)
    o[(size_t)(c0 + ty + i) * R + (r0 + tx)] = f2bf(t[tx][ty + i]);
}

// ---------- RMSNorm: f32 [4096][1024] -> bf16 ----------
__global__ __launch_bounds__(256) void k_rms(const float* __restrict__ x,
                                             const float* __restrict__ g,
                                             u16* __restrict__ o) {
  const int row = blockIdx.x, tid = threadIdx.x;
  const float4 v = ((const float4*)(x + (size_t)row * 1024))[tid];
  float ss = v.x * v.x + v.y * v.y + v.z * v.z + v.w * v.w;
#pragma unroll
  for (int ofs = 32; ofs > 0; ofs >>= 1) ss += __shfl_xor(ss, ofs);
  __shared__ float red[4];
  if ((tid & 63) == 0) red[tid >> 6] = ss;
  __syncthreads();
  const float s = rsqrtf((red[0] + red[1] + red[2] + red[3]) * (1.f / 1024.f) + 1e-5f);
  const float4 gv = ((const float4*)g)[tid];
  u32 lo = (u32)f2bf(v.x * s * gv.x) | ((u32)f2bf(v.y * s * gv.y) << 16);
  u32 hi = (u32)f2bf(v.z * s * gv.z) | ((u32)f2bf(v.w * s * gv.w) << 16);
  *(uint2*)(o + (size_t)row * 1024 + tid * 4) = make_uint2(lo, hi);
}

// ---------- GEMM: C[M,N] = A[M,K](bf16) @ Bt[N,K]^T(bf16), 128xTN, BK=32, 2-phase ----------
// EPI 0: bf16 out.  EPI 1: f32 out = acc + resid.
template <int EPI, int TN>
__global__ __launch_bounds__(256, 4) void k_gemm(const u16* __restrict__ A,
                                                 const u16* __restrict__ Bt,
                                                 u16* __restrict__ Obf,
                                                 float* __restrict__ Of,
                                                 const float* __restrict__ Rz,
                                                 int M, int N, int K) {
  constexpr int NFR = TN / 32;             // n-frags per wave (waves 2x2)
  __shared__ __align__(16) u16 As[2][128 * 32];
  __shared__ __align__(16) u16 Bs[2][TN * 32];
  const int tid = threadIdx.x;
  const int lane = tid & 63, wave = tid >> 6;
  const int wr = wave >> 1, wc = wave & 1;
  const int li = lane & 15, lg = lane >> 4;
  const int row0 = blockIdx.y * 128, col0 = blockIdx.x * TN;

  f32x4 acc[4][NFR] = {};
  const int sr = tid >> 2, sc = (tid & 3) * 8;
  const u16* ag = A + (size_t)(row0 + sr) * K + sc;
  const u16* bg = Bt + (size_t)(col0 + sr) * K + sc;
  const size_t rstep = (size_t)64 * K;

  // prologue: stage k0=0 into buf 0
  GLD16(ag, &As[0][tid * 8]);
  GLD16(ag + rstep, &As[0][tid * 8 + 2048]);
  GLD16(bg, &Bs[0][tid * 8]);
  if constexpr (TN == 128) GLD16(bg + rstep, &Bs[0][tid * 8 + 2048]);
  __syncthreads();                         // buf0 ready (vmcnt drain)

  int cur = 0;
  for (int k0 = 0; k0 < K; k0 += 32) {
    const int nxt = cur ^ 1;
    if (k0 + 32 < K) {                     // issue next-tile loads FIRST (T3 recipe)
      GLD16(ag + k0 + 32, &As[nxt][tid * 8]);
      GLD16(ag + rstep + k0 + 32, &As[nxt][tid * 8 + 2048]);
      GLD16(bg + k0 + 32, &Bs[nxt][tid * 8]);
      if constexpr (TN == 128) GLD16(bg + rstep + k0 + 32, &Bs[nxt][tid * 8 + 2048]);
    }
    short8 af[4], bfr[NFR];
#pragma unroll
    for (int m = 0; m < 4; ++m)
      af[m] = *(const short8*)(&As[cur][(wr * 64 + m * 16 + li) * 32 + lg * 8]);
#pragma unroll
    for (int n = 0; n < NFR; ++n)
      bfr[n] = *(const short8*)(&Bs[cur][(wc * (TN / 2) + n * 16 + li) * 32 + lg * 8]);
#pragma unroll
    for (int m = 0; m < 4; ++m)
#pragma unroll
      for (int n = 0; n < NFR; ++n)
        acc[m][n] = __builtin_amdgcn_mfma_f32_16x16x32_bf16(af[m], bfr[n], acc[m][n], 0, 0, 0);
    __syncthreads();                       // one drain per step, AFTER compute
    cur = nxt;
  }

#pragma unroll
  for (int m = 0; m < 4; ++m) {
    const int row = row0 + wr * 64 + m * 16 + lg * 4;
#pragma unroll
    for (int n = 0; n < NFR; ++n) {
      const int col = col0 + wc * (TN / 2) + n * 16 + li;
#pragma unroll
      for (int r = 0; r < 4; ++r) {
        const size_t idx = (size_t)(row + r) * N + col;
        if (EPI == 0) Obf[idx] = f2bf(acc[m][n][r]);
        else          Of[idx] = acc[m][n][r] + Rz[idx];
      }
    }
  }
}

// ---------- fused SwiGLU FFN13: O = bf16( silu(A@B1^T)*(A@B3^T) ), 128x64, BK=32, 2-phase ----------
__global__ __launch_bounds__(256, 4) void k_ffn13(const u16* __restrict__ A,
                                                  const u16* __restrict__ B1,
                                                  const u16* __restrict__ B3,
                                                  u16* __restrict__ O,
                                                  int M, int N, int K) {
  __shared__ __align__(16) u16 As[2][128 * 32];
  __shared__ __align__(16) u16 B1s[2][64 * 32];
  __shared__ __align__(16) u16 B3s[2][64 * 32];
  const int tid = threadIdx.x;
  const int lane = tid & 63, wave = tid >> 6;
  const int wr = wave >> 1, wc = wave & 1;
  const int li = lane & 15, lg = lane >> 4;
  const int row0 = blockIdx.y * 128, col0 = blockIdx.x * 64;

  f32x4 a1[4][2] = {}, a3[4][2] = {};
  const int sr = tid >> 2, sc = (tid & 3) * 8;
  const u16* ag = A + (size_t)(row0 + sr) * K + sc;
  const u16* b1g = B1 + (size_t)(col0 + sr) * K + sc;
  const u16* b3g = B3 + (size_t)(col0 + sr) * K + sc;
  const size_t rstep = (size_t)64 * K;

  // prologue: stage k0=0 into buf 0
  GLD16(ag, &As[0][tid * 8]);
  GLD16(ag + rstep, &As[0][tid * 8 + 2048]);
  GLD16(b1g, &B1s[0][tid * 8]);
  GLD16(b3g, &B3s[0][tid * 8]);
  __syncthreads();

  int cur = 0;
  for (int k0 = 0; k0 < K; k0 += 32) {
    const int nxt = cur ^ 1;
    if (k0 + 32 < K) {
      GLD16(ag + k0 + 32, &As[nxt][tid * 8]);
      GLD16(ag + rstep + k0 + 32, &As[nxt][tid * 8 + 2048]);
      GLD16(b1g + k0 + 32, &B1s[nxt][tid * 8]);
      GLD16(b3g + k0 + 32, &B3s[nxt][tid * 8]);
    }
    short8 af[4], b1f[2], b3f[2];
#pragma unroll
    for (int m = 0; m < 4; ++m)
      af[m] = *(const short8*)(&As[cur][(wr * 64 + m * 16 + li) * 32 + lg * 8]);
#pragma unroll
    for (int n = 0; n < 2; ++n) {
      b1f[n] = *(const short8*)(&B1s[cur][(wc * 32 + n * 16 + li) * 32 + lg * 8]);
      b3f[n] = *(const short8*)(&B3s[cur][(wc * 32 + n * 16 + li) * 32 + lg * 8]);
    }
#pragma unroll
    for (int m = 0; m < 4; ++m)
#pragma unroll
      for (int n = 0; n < 2; ++n) {
        a1[m][n] = __builtin_amdgcn_mfma_f32_16x16x32_bf16(af[m], b1f[n], a1[m][n], 0, 0, 0);
        a3[m][n] = __builtin_amdgcn_mfma_f32_16x16x32_bf16(af[m], b3f[n], a3[m][n], 0, 0, 0);
      }
    __syncthreads();
    cur = nxt;
  }

#pragma unroll
  for (int m = 0; m < 4; ++m) {
    const int row = row0 + wr * 64 + m * 16 + lg * 4;
#pragma unroll
    for (int n = 0; n < 2; ++n) {
      const int col = col0 + wc * 32 + n * 16 + li;
#pragma unroll
      for (int r = 0; r < 4; ++r) {
        const float g1 = a1[m][n][r], g3 = a3[m][n][r];
        const float sl = g1 / (1.f + __expf(-g1));
        O[(size_t)(row + r) * N + col] = f2bf(sl * g3);
      }
    }
  }
}

// ---------- flash attention pass 1 (causal, split kv + paired qb) ----------
// Verified 2-barrier-per-tile skeleton. Fixed-max softmax. T14 reg-staged K/V.
__global__ __launch_bounds__(512) void k_attn(const u16* __restrict__ qkv,
                                              u16* __restrict__ Opart,
                                              float* __restrict__ ml) {
  const int LD = 3072;
  const int b = blockIdx.x;
  const int h = b & 15;
  const int p = (b >> 4) >> 1;
  const int j = (b >> 4) & 1;
  const int tid = threadIdx.x, lane = tid & 63, w = tid >> 6;
  const int li = lane & 15, lg = lane >> 4;
  const int swzB = (li & 7) << 4;
  const float QS = 0.125f * 1.44269504f;
  const float FM = 12.0f;                         // fixed softmax max (log2 units)

  __shared__ __align__(16) u16 Ks[64 * 64];       // [key][d], swizzled
  __shared__ __align__(16) u16 Vt[64 * 64];       // [d][key], swizzled
  __shared__ __align__(16) u16 Ps[8 * 16 * 64];   // per-wave [q][key], swizzled

  const int krow = tid >> 3;
  const u16* kg = qkv + 1024 + h * 64 + ((tid & 7) ^ (krow & 7)) * 8;
  u16* klds = Ks + tid * 8;                       // linear dest (source pre-swizzled)

  const int vd0 = (tid & 31) * 2;
  const int vkq = tid >> 5;                       // 0..15, 4 keys each
  const u16* vg = qkv + 2048 + h * 64 + vd0;
  u16* vl0 = Vt + (size_t)vd0 * 64 + (((vkq * 8) ^ ((vd0 & 7) << 4)) >> 1);
  u16* vl1 = Vt + (size_t)(vd0 + 1) * 64 + (((vkq * 8) ^ (((vd0 + 1) & 7) << 4)) >> 1);
  u16* pw = Ps + w * 1024 + li * 64;

  for (int sub = 0; sub < 2; ++sub) {
    const int qb = sub ? (31 - p) : p;
    const int q0 = qb * 128;
    const int t0 = j ? (qb + 1) : 0;
    const int t1 = j ? (2 * qb + 2) : (qb + 1);
    const int qrow = q0 + w * 16 + li;
    const int wqmax = q0 + w * 16 + 15;

    const u16* qp = qkv + (size_t)qrow * LD + h * 64;
    short8 qf0, qf1;
#pragma unroll
    for (int jj = 0; jj < 8; ++jj) {
      qf0[jj] = (short)f2bf(bf2f(qp[lg * 8 + jj]) * QS);
      qf1[jj] = (short)f2bf(bf2f(qp[32 + lg * 8 + jj]) * QS);
    }

    float lsm = 0.f;
    f32x4 accO[4] = {};
    uint4 kld;
    u32 vld[4];
    // prologue: issue K+V loads for tile t0
    kld = *(const uint4*)(kg + (size_t)(t0 * 64 + krow) * LD);
#pragma unroll
    for (int i = 0; i < 4; ++i)
      vld[i] = *(const u32*)(vg + (size_t)(t0 * 64 + vkq * 4 + i) * LD);

    for (int t = t0; t < t1; ++t) {
      const int k0 = t * 64;
      __syncthreads();                  // (A) all waves done reading prev tile
      *(uint4*)klds = kld;              // K: reg -> LDS (b128 write)
      {                                 // V: pack + swizzled write
        u32 lo0 = (vld[0] & 0xffffu) | (vld[1] << 16);
        u32 lo1 = (vld[2] & 0xffffu) | (vld[3] << 16);
        u32 hi0 = (vld[0] >> 16) | (vld[1] & 0xffff0000u);
        u32 hi1 = (vld[2] >> 16) | (vld[3] & 0xffff0000u);
        *(uint2*)vl0 = make_uint2(lo0, lo1);
        *(uint2*)vl1 = make_uint2(hi0, hi1);
      }
      __syncthreads();                  // (B) tile visible
      if (t + 1 < t1) {                 // T14: issue next-tile K+V loads
        kld = *(const uint4*)(kg + (size_t)((t + 1) * 64 + krow) * LD);
        const u16* vp = vg + (size_t)(t + 1) * 64 * LD;
#pragma unroll
        for (int i = 0; i < 4; ++i) vld[i] = *(const u32*)(vp + (size_t)(vkq * 4 + i) * LD);
      }

      if (k0 <= wqmax) {  // wave-uniform
        // ---- QK^T: st[key][q] = K@Q^T (log2-scaled) - FM (bias via C-init) ----
        f32x4 st[4];
#pragma unroll
        for (int f = 0; f < 4; ++f) {
          const u16* kp = Ks + (size_t)(f * 16 + li) * 64;
          const short8 ka0 = *(const short8*)(kp + (((lg * 16) ^ swzB) >> 1));
          const short8 ka1 = *(const short8*)(kp + (((64 + lg * 16) ^ swzB) >> 1));
          f32x4 z = {-FM, -FM, -FM, -FM};
          z = __builtin_amdgcn_mfma_f32_16x16x32_bf16(ka0, qf0, z, 0, 0, 0);
          st[f] = __builtin_amdgcn_mfma_f32_16x16x32_bf16(ka1, qf1, z, 0, 0, 0);
        }
        // ---- fixed-max softmax: mask diagonal in place, p = exp2(st) ----
        if (!(k0 + 63 <= q0 + w * 16)) {  // diagonal tile for this wave
#pragma unroll
          for (int f = 0; f < 4; ++f)
#pragma unroll
            for (int r = 0; r < 4; ++r) {
              const int kg2 = k0 + f * 16 + lg * 4 + r;
              if (kg2 > qrow) st[f][r] = -1e30f;
            }
        }
        float psum = 0.f;
#pragma unroll
        for (int f = 0; f < 4; ++f) {
          const float p0 = __builtin_amdgcn_exp2f(st[f][0]);
          const float p1 = __builtin_amdgcn_exp2f(st[f][1]);
          const float p2 = __builtin_amdgcn_exp2f(st[f][2]);
          const float p3 = __builtin_amdgcn_exp2f(st[f][3]);
          psum += (p0 + p1) + (p2 + p3);
          *(uint2*)(pw + (((f * 32 + lg * 8) ^ swzB) >> 1)) =
              make_uint2(pk_bf16(p0, p1), pk_bf16(p2, p3));
        }
        psum += __shfl_xor(psum, 16);
        psum += __shfl_xor(psum, 32);
        lsm += psum;

        // ---- PV: O^T[d][q] += V^T @ P^T ----
#pragma unroll
        for (int kk = 0; kk < 2; ++kk) {
          const int cofs = ((kk * 64 + lg * 16) ^ swzB) >> 1;
          const short8 pf = *(const short8*)(pw + cofs);
#pragma unroll
          for (int n = 0; n < 4; ++n) {
            const short8 vf = *(const short8*)(Vt + (size_t)(n * 16 + li) * 64 + cofs);
            accO[n] = __builtin_amdgcn_mfma_f32_16x16x32_bf16(vf, pf, accO[n], 0, 0, 0);
          }
        }
      }
    }

    // ---- store partials (unnormalized, bf16) ----
    const int item = (h * 32 + qb) * 2 + j;
    u16* op = Opart + (size_t)item * 8192 + (w * 16 + li) * 64 + lg * 4;
#pragma unroll
    for (int n = 0; n < 4; ++n)
      *(uint2*)(op + n * 16) = make_uint2(pk_bf16(accO[n][0], accO[n][1]),
                                          pk_bf16(accO[n][2], accO[n][3]));
    if (lg == 0) ml[item * 128 + w * 16 + li] = lsm;
  }
}

// ---------- flash attention pass 2: merge halves (same fixed max -> plain sum) ----------
__global__ __launch_bounds__(256) void k_amerge(const u16* __restrict__ Opart,
                                                const float* __restrict__ ml,
                                                u16* __restrict__ o) {
  const int b = blockIdx.x;             // 512 = 16 h x 32 qb
  const int h = b & 15, qb = b >> 4;
  const int q = threadIdx.x >> 1;
  const int dh = (threadIdx.x & 1) * 32;
  const int i0 = (h * 32 + qb) * 2;
  const float l0 = ml[i0 * 128 + q];
  const float l1 = ml[(i0 + 1) * 128 + q];
  const float r = 1.f / (l0 + l1);
  const u16* p0 = Opart + (size_t)i0 * 8192 + q * 64 + dh;
  const u16* p1 = p0 + 8192;
  u16* op = o + (size_t)(qb * 128 + q) * 1024 + h * 64 + dh;
#pragma unroll
  for (int dd = 0; dd < 32; dd += 4) {
    const uint2 a = *(const uint2*)(p0 + dd);
    const uint2 c = *(const uint2*)(p1 + dd);
    const float s0 = bf2f((u16)a.x) + bf2f((u16)c.x);
    const float s1 = bf2f((u16)(a.x >> 16)) + bf2f((u16)(c.x >> 16));
    const float s2 = bf2f((u16)a.y) + bf2f((u16)c.y);
    const float s3 = bf2f((u16)(a.y >> 16)) + bf2f((u16)(c.y >> 16));
    *(uint2*)(op + dd) = make_uint2(pk_bf16(s0 * r, s1 * r), pk_bf16(s2 * r, s3 * r));
  }
}

extern "C" void kernel_launch(void* const* d_in, const int* in_sizes, int n_in,
                              void* d_out, int out_size, void* d_ws, size_t ws_size,
                              hipStream_t stream) {
  const float* x  = (const float*)d_in[0];
  const float* wq = (const float*)d_in[1];
  const float* wk = (const float*)d_in[2];
  const float* wv = (const float*)d_in[3];
  const float* wo = (const float*)d_in[4];
  const float* w1 = (const float*)d_in[5];
  const float* w2 = (const float*)d_in[6];   // w2 before w3 in dict order
  const float* w3 = (const float*)d_in[7];
  const float* ga = (const float*)d_in[8];
  const float* gf = (const float*)d_in[9];
  float* out = (float*)d_out;

  char* p = (char*)d_ws;
  auto take = [&](size_t n) { char* r = p; p += (n + 255) & ~(size_t)255; return r; };
  u16* wqkvo_t = (u16*)take(4ull * 1024 * 1024 * 2);   // 4 x [1024][1024] bf16
  u16* w13_t   = (u16*)take(2ull * 2816 * 1024 * 2);   // w1^T then w3^T
  u16* w2_t    = (u16*)take(1024ull * 2816 * 2);
  u16* xn      = (u16*)take(4096ull * 1024 * 2);
  u16* qkvb    = (u16*)take(4096ull * 3072 * 2);
  u16* atn     = (u16*)take(4096ull * 1024 * 2);
  // union region: {Opart 16.8MB bf16 + ml 0.5MB} (attn passes) vs {hb, hn, ffb} (post-attn)
  char* uni    = take(48234496);
  u16* Opart   = (u16*)uni;                            // 1024 items x 8192 bf16
  float* mlb   = (float*)(uni + 1024ull * 8192 * 2);   // 1024 items x 128 f32
  float* hb    = (float*)uni;                          // 4096x1024 f32
  u16* hn      = (u16*)(uni + 4096ull * 1024 * 4);     // 4096x1024 bf16
  u16* ffb     = (u16*)(uni + 4096ull * 1024 * 6);     // 4096x2816 bf16

  u16* wqkv_t = wqkvo_t;
  u16* wo_t   = wqkvo_t + 3ull * 1024 * 1024;
  u16* w1_t   = w13_t;
  u16* w3_t   = w13_t + 2816ull * 1024;

  k_tc4<<<dim3(32, 32, 4), 256, 0, stream>>>(wq, wk, wv, wo, wqkvo_t, 1024, 1024);
  k_tc4<<<dim3(88, 32, 2), 256, 0, stream>>>(w1, w3, w1, w3, w13_t, 1024, 2816);
  k_tc4<<<dim3(32, 88, 1), 256, 0, stream>>>(w2, w2, w2, w2, w2_t, 2816, 1024);

  k_rms<<<4096, 256, 0, stream>>>(x, ga, xn);
  k_gemm<0, 128><<<dim3(24, 32), 256, 0, stream>>>(xn, wqkv_t, qkvb, nullptr, nullptr, 4096, 3072, 1024);
  k_attn<<<512, 512, 0, stream>>>(qkvb, Opart, mlb);
  k_amerge<<<512, 256, 0, stream>>>(Opart, mlb, atn);
  k_gemm<1, 64><<<dim3(16, 32), 256, 0, stream>>>(atn, wo_t, nullptr, hb, x, 4096, 1024, 1024);
  k_rms<<<4096, 256, 0, stream>>>(hb, gf, hn);
  k_ffn13<<<dim3(44, 32), 256, 0, stream>>>(hn, w1_t, w3_t, ffb, 4096, 2816, 1024);
  k_gemm<1, 64><<<dim3(16, 32), 256, 0, stream>>>(ffb, w2_t, nullptr, out, hb, 4096, 1024, 2816);
}

// Round 13
// 260.335 us; speedup vs baseline: 1.0175x; 1.0175x over previous
//
#include <hip/hip_runtime.h>
#include <stdint.h>

// TransformerBlock: x:[1,4096,1024] f32 -> out f32
// DIM=1024 NH=16 HD=64 HIDDEN=2816 SEQ=4096 eps=1e-5
// bf16 MFMA GEMMs (BK=32, 2-phase dbuf) + flash attention (flash-decoding split,
// unpaired 1024-block heavy-first, fixed-max softmax, bf16 partials).

typedef unsigned short u16;
typedef unsigned int u32;
typedef __attribute__((ext_vector_type(8))) short short8;   // 8 x bf16 (4 VGPR)
typedef __attribute__((ext_vector_type(4))) float f32x4;

#define GLD16(G, L) __builtin_amdgcn_global_load_lds( \
    (__attribute__((address_space(1))) void*)(G),      \
    (__attribute__((address_space(3))) void*)(L), 16, 0, 0)

__device__ __forceinline__ u16 f2bf(float f) {  // RNE
  u32 u = __builtin_bit_cast(u32, f);
  u32 r = u + 0x7fffu + ((u >> 16) & 1u);
  return (u16)(r >> 16);
}
__device__ __forceinline__ float bf2f(u16 b) {
  u32 u = (u32)b << 16;
  return __builtin_bit_cast(float, u);
}
__device__ __forceinline__ u32 pk_bf16(float lo, float hi) {  // T12
  u32 r;
  asm("v_cvt_pk_bf16_f32 %0, %1, %2" : "=v"(r) : "v"(lo), "v"(hi));
  return r;
}

// ---------- fused weight prep: all 7 transposes (f32 -> bf16^T), range-decoded ----------
__global__ __launch_bounds__(256) void k_prep(const float* __restrict__ wq,
                                              const float* __restrict__ wk,
                                              const float* __restrict__ wv,
                                              const float* __restrict__ wo,
                                              const float* __restrict__ w1,
                                              const float* __restrict__ w3,
                                              const float* __restrict__ w2f,
                                              u16* __restrict__ wqkvo_t,
                                              u16* __restrict__ w13_t,
                                              u16* __restrict__ w2_t) {
  const int bid = blockIdx.x;
  const float* in;
  u16* o;
  int R, C, c0, r0;
  if (bid < 4096) {                       // wq,wk,wv,wo: [1024][1024]
    const int z = bid >> 10, r = bid & 1023;
    in = (z == 0) ? wq : (z == 1) ? wk : (z == 2) ? wv : wo;
    o = wqkvo_t + (size_t)z * 1024 * 1024;
    R = 1024; C = 1024;
    c0 = (r & 31) * 32; r0 = (r >> 5) * 32;
  } else if (bid < 9728) {                // w1,w3: [1024][2816]
    int r = bid - 4096;
    const int z = r / 2816; r %= 2816;
    in = z ? w3 : w1;
    o = w13_t + (size_t)z * 2816 * 1024;
    R = 1024; C = 2816;
    c0 = (r % 88) * 32; r0 = (r / 88) * 32;
  } else {                                // w2: [2816][1024]
    const int r = bid - 9728;
    in = w2f; o = w2_t;
    R = 2816; C = 1024;
    c0 = (r & 31) * 32; r0 = (r >> 5) * 32;
  }
  __shared__ float t[32][33];
  const int tx = threadIdx.x & 31, ty = threadIdx.x >> 5;
#pragma unroll
  for (int i = 0; i < 32; i += 8)
    t[ty + i][tx] = in[(size_t)(r0 + ty + i) * C + (c0 + tx)];
  __syncthreads();
#pragma unroll
  for (int i = 0; i < 32; i += 8)
    o[(size_t)(c0 + ty + i) * R + (r0 + tx)] = f2bf(t[tx][ty + i]);
}

// ---------- RMSNorm: f32 [4096][1024] -> bf16 ----------
__global__ __launch_bounds__(256) void k_rms(const float* __restrict__ x,
                                             const float* __restrict__ g,
                                             u16* __restrict__ o) {
  const int row = blockIdx.x, tid = threadIdx.x;
  const float4 v = ((const float4*)(x + (size_t)row * 1024))[tid];
  float ss = v.x * v.x + v.y * v.y + v.z * v.z + v.w * v.w;
#pragma unroll
  for (int ofs = 32; ofs > 0; ofs >>= 1) ss += __shfl_xor(ss, ofs);
  __shared__ float red[4];
  if ((tid & 63) == 0) red[tid >> 6] = ss;
  __syncthreads();
  const float s = rsqrtf((red[0] + red[1] + red[2] + red[3]) * (1.f / 1024.f) + 1e-5f);
  const float4 gv = ((const float4*)g)[tid];
  u32 lo = (u32)f2bf(v.x * s * gv.x) | ((u32)f2bf(v.y * s * gv.y) << 16);
  u32 hi = (u32)f2bf(v.z * s * gv.z) | ((u32)f2bf(v.w * s * gv.w) << 16);
  *(uint2*)(o + (size_t)row * 1024 + tid * 4) = make_uint2(lo, hi);
}

// ---------- GEMM: C[M,N] = A[M,K](bf16) @ Bt[N,K]^T(bf16), 128xTN, BK=32, 2-phase ----------
// EPI 0: bf16 out.  EPI 1: f32 out = acc + resid.
template <int EPI, int TN>
__global__ __launch_bounds__(256) void k_gemm(const u16* __restrict__ A,
                                              const u16* __restrict__ Bt,
                                              u16* __restrict__ Obf,
                                              float* __restrict__ Of,
                                              const float* __restrict__ Rz,
                                              int M, int N, int K) {
  constexpr int NFR = TN / 32;             // n-frags per wave (waves 2x2)
  __shared__ __align__(16) u16 As[2][128 * 32];
  __shared__ __align__(16) u16 Bs[2][TN * 32];
  const int tid = threadIdx.x;
  const int lane = tid & 63, wave = tid >> 6;
  const int wr = wave >> 1, wc = wave & 1;
  const int li = lane & 15, lg = lane >> 4;
  const int row0 = blockIdx.y * 128, col0 = blockIdx.x * TN;

  f32x4 acc[4][NFR] = {};
  const int sr = tid >> 2, sc = (tid & 3) * 8;
  const u16* ag = A + (size_t)(row0 + sr) * K + sc;
  const u16* bg = Bt + (size_t)(col0 + sr) * K + sc;
  const size_t rstep = (size_t)64 * K;

  // prologue: stage k0=0 into buf 0
  GLD16(ag, &As[0][tid * 8]);
  GLD16(ag + rstep, &As[0][tid * 8 + 2048]);
  GLD16(bg, &Bs[0][tid * 8]);
  if constexpr (TN == 128) GLD16(bg + rstep, &Bs[0][tid * 8 + 2048]);
  __syncthreads();                         // buf0 ready (vmcnt drain)

  int cur = 0;
  for (int k0 = 0; k0 < K; k0 += 32) {
    const int nxt = cur ^ 1;
    if (k0 + 32 < K) {                     // issue next-tile loads FIRST (T3 recipe)
      GLD16(ag + k0 + 32, &As[nxt][tid * 8]);
      GLD16(ag + rstep + k0 + 32, &As[nxt][tid * 8 + 2048]);
      GLD16(bg + k0 + 32, &Bs[nxt][tid * 8]);
      if constexpr (TN == 128) GLD16(bg + rstep + k0 + 32, &Bs[nxt][tid * 8 + 2048]);
    }
    short8 af[4], bfr[NFR];
#pragma unroll
    for (int m = 0; m < 4; ++m)
      af[m] = *(const short8*)(&As[cur][(wr * 64 + m * 16 + li) * 32 + lg * 8]);
#pragma unroll
    for (int n = 0; n < NFR; ++n)
      bfr[n] = *(const short8*)(&Bs[cur][(wc * (TN / 2) + n * 16 + li) * 32 + lg * 8]);
#pragma unroll
    for (int m = 0; m < 4; ++m)
#pragma unroll
      for (int n = 0; n < NFR; ++n)
        acc[m][n] = __builtin_amdgcn_mfma_f32_16x16x32_bf16(af[m], bfr[n], acc[m][n], 0, 0, 0);
    __syncthreads();                       // one drain per step, AFTER compute
    cur = nxt;
  }

#pragma unroll
  for (int m = 0; m < 4; ++m) {
    const int row = row0 + wr * 64 + m * 16 + lg * 4;
#pragma unroll
    for (int n = 0; n < NFR; ++n) {
      const int col = col0 + wc * (TN / 2) + n * 16 + li;
#pragma unroll
      for (int r = 0; r < 4; ++r) {
        const size_t idx = (size_t)(row + r) * N + col;
        if (EPI == 0) Obf[idx] = f2bf(acc[m][n][r]);
        else          Of[idx] = acc[m][n][r] + Rz[idx];
      }
    }
  }
}

// ---------- fused SwiGLU FFN13: O = bf16( silu(A@B1^T)*(A@B3^T) ), 128x64, BK=32, 2-phase ----------
__global__ __launch_bounds__(256) void k_ffn13(const u16* __restrict__ A,
                                               const u16* __restrict__ B1,
                                               const u16* __restrict__ B3,
                                               u16* __restrict__ O,
                                               int M, int N, int K) {
  __shared__ __align__(16) u16 As[2][128 * 32];
  __shared__ __align__(16) u16 B1s[2][64 * 32];
  __shared__ __align__(16) u16 B3s[2][64 * 32];
  const int tid = threadIdx.x;
  const int lane = tid & 63, wave = tid >> 6;
  const int wr = wave >> 1, wc = wave & 1;
  const int li = lane & 15, lg = lane >> 4;
  const int row0 = blockIdx.y * 128, col0 = blockIdx.x * 64;

  f32x4 a1[4][2] = {}, a3[4][2] = {};
  const int sr = tid >> 2, sc = (tid & 3) * 8;
  const u16* ag = A + (size_t)(row0 + sr) * K + sc;
  const u16* b1g = B1 + (size_t)(col0 + sr) * K + sc;
  const u16* b3g = B3 + (size_t)(col0 + sr) * K + sc;
  const size_t rstep = (size_t)64 * K;

  // prologue: stage k0=0 into buf 0
  GLD16(ag, &As[0][tid * 8]);
  GLD16(ag + rstep, &As[0][tid * 8 + 2048]);
  GLD16(b1g, &B1s[0][tid * 8]);
  GLD16(b3g, &B3s[0][tid * 8]);
  __syncthreads();

  int cur = 0;
  for (int k0 = 0; k0 < K; k0 += 32) {
    const int nxt = cur ^ 1;
    if (k0 + 32 < K) {
      GLD16(ag + k0 + 32, &As[nxt][tid * 8]);
      GLD16(ag + rstep + k0 + 32, &As[nxt][tid * 8 + 2048]);
      GLD16(b1g + k0 + 32, &B1s[nxt][tid * 8]);
      GLD16(b3g + k0 + 32, &B3s[nxt][tid * 8]);
    }
    short8 af[4], b1f[2], b3f[2];
#pragma unroll
    for (int m = 0; m < 4; ++m)
      af[m] = *(const short8*)(&As[cur][(wr * 64 + m * 16 + li) * 32 + lg * 8]);
#pragma unroll
    for (int n = 0; n < 2; ++n) {
      b1f[n] = *(const short8*)(&B1s[cur][(wc * 32 + n * 16 + li) * 32 + lg * 8]);
      b3f[n] = *(const short8*)(&B3s[cur][(wc * 32 + n * 16 + li) * 32 + lg * 8]);
    }
#pragma unroll
    for (int m = 0; m < 4; ++m)
#pragma unroll
      for (int n = 0; n < 2; ++n) {
        a1[m][n] = __builtin_amdgcn_mfma_f32_16x16x32_bf16(af[m], b1f[n], a1[m][n], 0, 0, 0);
        a3[m][n] = __builtin_amdgcn_mfma_f32_16x16x32_bf16(af[m], b3f[n], a3[m][n], 0, 0, 0);
      }
    __syncthreads();
    cur = nxt;
  }

#pragma unroll
  for (int m = 0; m < 4; ++m) {
    const int row = row0 + wr * 64 + m * 16 + lg * 4;
#pragma unroll
    for (int n = 0; n < 2; ++n) {
      const int col = col0 + wc * 32 + n * 16 + li;
#pragma unroll
      for (int r = 0; r < 4; ++r) {
        const float g1 = a1[m][n][r], g3 = a3[m][n][r];
        const float sl = g1 / (1.f + __expf(-g1));
        O[(size_t)(row + r) * N + col] = f2bf(sl * g3);
      }
    }
  }
}

// ---------- flash attention pass 1 (causal, split kv, unpaired heavy-first) ----------
// Verified 2-barrier-per-tile skeleton. Fixed-max softmax. T14 reg-staged K/V.
// 1024 blocks = (h, qb, j), heaviest qb dispatched first; 4 blocks/CU resident.
__global__ __launch_bounds__(512) void k_attn(const u16* __restrict__ qkv,
                                              u16* __restrict__ Opart,
                                              float* __restrict__ ml) {
  const int LD = 3072;
  const int bid = blockIdx.x;
  const int qb = 31 - (bid >> 5);                 // heavy q-blocks first
  const int h = (bid >> 1) & 15;
  const int j = bid & 1;
  const int tid = threadIdx.x, lane = tid & 63, w = tid >> 6;
  const int li = lane & 15, lg = lane >> 4;
  const int swzB = (li & 7) << 4;
  const float QS = 0.125f * 1.44269504f;
  const float FM = 12.0f;                         // fixed softmax max (log2 units)

  __shared__ __align__(16) u16 Ks[64 * 64];       // [key][d], swizzled
  __shared__ __align__(16) u16 Vt[64 * 64];       // [d][key], swizzled
  __shared__ __align__(16) u16 Ps[8 * 16 * 64];   // per-wave [q][key], swizzled

  const int krow = tid >> 3;
  const u16* kg = qkv + 1024 + h * 64 + ((tid & 7) ^ (krow & 7)) * 8;
  u16* klds = Ks + tid * 8;                       // linear dest (source pre-swizzled)

  const int vd0 = (tid & 31) * 2;
  const int vkq = tid >> 5;                       // 0..15, 4 keys each
  const u16* vg = qkv + 2048 + h * 64 + vd0;
  u16* vl0 = Vt + (size_t)vd0 * 64 + (((vkq * 8) ^ ((vd0 & 7) << 4)) >> 1);
  u16* vl1 = Vt + (size_t)(vd0 + 1) * 64 + (((vkq * 8) ^ (((vd0 + 1) & 7) << 4)) >> 1);
  u16* pw = Ps + w * 1024 + li * 64;

  const int q0 = qb * 128;
  const int t0 = j ? (qb + 1) : 0;
  const int t1 = j ? (2 * qb + 2) : (qb + 1);
  const int qrow = q0 + w * 16 + li;
  const int wqmax = q0 + w * 16 + 15;

  const u16* qp = qkv + (size_t)qrow * LD + h * 64;
  short8 qf0, qf1;
#pragma unroll
  for (int jj = 0; jj < 8; ++jj) {
    qf0[jj] = (short)f2bf(bf2f(qp[lg * 8 + jj]) * QS);
    qf1[jj] = (short)f2bf(bf2f(qp[32 + lg * 8 + jj]) * QS);
  }

  float lsm = 0.f;
  f32x4 accO[4] = {};
  uint4 kld;
  u32 vld[4];
  // prologue: issue K+V loads for tile t0
  kld = *(const uint4*)(kg + (size_t)(t0 * 64 + krow) * LD);
#pragma unroll
  for (int i = 0; i < 4; ++i)
    vld[i] = *(const u32*)(vg + (size_t)(t0 * 64 + vkq * 4 + i) * LD);

  for (int t = t0; t < t1; ++t) {
    const int k0 = t * 64;
    __syncthreads();                  // (A) all waves done reading prev tile
    *(uint4*)klds = kld;              // K: reg -> LDS (b128 write)
    {                                 // V: pack + swizzled write
      u32 lo0 = (vld[0] & 0xffffu) | (vld[1] << 16);
      u32 lo1 = (vld[2] & 0xffffu) | (vld[3] << 16);
      u32 hi0 = (vld[0] >> 16) | (vld[1] & 0xffff0000u);
      u32 hi1 = (vld[2] >> 16) | (vld[3] & 0xffff0000u);
      *(uint2*)vl0 = make_uint2(lo0, lo1);
      *(uint2*)vl1 = make_uint2(hi0, hi1);
    }
    __syncthreads();                  // (B) tile visible
    if (t + 1 < t1) {                 // T14: issue next-tile K+V loads
      kld = *(const uint4*)(kg + (size_t)((t + 1) * 64 + krow) * LD);
      const u16* vp = vg + (size_t)(t + 1) * 64 * LD;
#pragma unroll
      for (int i = 0; i < 4; ++i) vld[i] = *(const u32*)(vp + (size_t)(vkq * 4 + i) * LD);
    }

    if (k0 <= wqmax) {  // wave-uniform
      // ---- QK^T: st[key][q] = K@Q^T (log2-scaled) - FM (bias via C-init) ----
      f32x4 st[4];
#pragma unroll
      for (int f = 0; f < 4; ++f) {
        const u16* kp = Ks + (size_t)(f * 16 + li) * 64;
        const short8 ka0 = *(const short8*)(kp + (((lg * 16) ^ swzB) >> 1));
        const short8 ka1 = *(const short8*)(kp + (((64 + lg * 16) ^ swzB) >> 1));
        f32x4 z = {-FM, -FM, -FM, -FM};
        z = __builtin_amdgcn_mfma_f32_16x16x32_bf16(ka0, qf0, z, 0, 0, 0);
        st[f] = __builtin_amdgcn_mfma_f32_16x16x32_bf16(ka1, qf1, z, 0, 0, 0);
      }
      // ---- fixed-max softmax: mask diagonal in place, p = exp2(st) ----
      if (!(k0 + 63 <= q0 + w * 16)) {  // diagonal tile for this wave
#pragma unroll
        for (int f = 0; f < 4; ++f)
#pragma unroll
          for (int r = 0; r < 4; ++r) {
            const int kg2 = k0 + f * 16 + lg * 4 + r;
            if (kg2 > qrow) st[f][r] = -1e30f;
          }
      }
      float psum = 0.f;
#pragma unroll
      for (int f = 0; f < 4; ++f) {
        const float p0 = __builtin_amdgcn_exp2f(st[f][0]);
        const float p1 = __builtin_amdgcn_exp2f(st[f][1]);
        const float p2 = __builtin_amdgcn_exp2f(st[f][2]);
        const float p3 = __builtin_amdgcn_exp2f(st[f][3]);
        psum += (p0 + p1) + (p2 + p3);
        *(uint2*)(pw + (((f * 32 + lg * 8) ^ swzB) >> 1)) =
            make_uint2(pk_bf16(p0, p1), pk_bf16(p2, p3));
      }
      psum += __shfl_xor(psum, 16);
      psum += __shfl_xor(psum, 32);
      lsm += psum;

      // ---- PV: O^T[d][q] += V^T @ P^T ----
#pragma unroll
      for (int kk = 0; kk < 2; ++kk) {
        const int cofs = ((kk * 64 + lg * 16) ^ swzB) >> 1;
        const short8 pf = *(const short8*)(pw + cofs);
#pragma unroll
        for (int n = 0; n < 4; ++n) {
          const short8 vf = *(const short8*)(Vt + (size_t)(n * 16 + li) * 64 + cofs);
          accO[n] = __builtin_amdgcn_mfma_f32_16x16x32_bf16(vf, pf, accO[n], 0, 0, 0);
        }
      }
    }
  }

  // ---- store partials (unnormalized, bf16) ----
  const int item = (h * 32 + qb) * 2 + j;
  u16* op = Opart + (size_t)item * 8192 + (w * 16 + li) * 64 + lg * 4;
#pragma unroll
  for (int n = 0; n < 4; ++n)
    *(uint2*)(op + n * 16) = make_uint2(pk_bf16(accO[n][0], accO[n][1]),
                                        pk_bf16(accO[n][2], accO[n][3]));
  if (lg == 0) ml[item * 128 + w * 16 + li] = lsm;
}

// ---------- flash attention pass 2: merge halves (same fixed max -> plain sum) ----------
__global__ __launch_bounds__(256) void k_amerge(const u16* __restrict__ Opart,
                                                const float* __restrict__ ml,
                                                u16* __restrict__ o) {
  const int b = blockIdx.x;             // 512 = 16 h x 32 qb
  const int h = b & 15, qb = b >> 4;
  const int q = threadIdx.x >> 1;
  const int dh = (threadIdx.x & 1) * 32;
  const int i0 = (h * 32 + qb) * 2;
  const float l0 = ml[i0 * 128 + q];
  const float l1 = ml[(i0 + 1) * 128 + q];
  const float r = 1.f / (l0 + l1);
  const u16* p0 = Opart + (size_t)i0 * 8192 + q * 64 + dh;
  const u16* p1 = p0 + 8192;
  u16* op = o + (size_t)(qb * 128 + q) * 1024 + h * 64 + dh;
#pragma unroll
  for (int dd = 0; dd < 32; dd += 4) {
    const uint2 a = *(const uint2*)(p0 + dd);
    const uint2 c = *(const uint2*)(p1 + dd);
    const float s0 = bf2f((u16)a.x) + bf2f((u16)c.x);
    const float s1 = bf2f((u16)(a.x >> 16)) + bf2f((u16)(c.x >> 16));
    const float s2 = bf2f((u16)a.y) + bf2f((u16)c.y);
    const float s3 = bf2f((u16)(a.y >> 16)) + bf2f((u16)(c.y >> 16));
    *(uint2*)(op + dd) = make_uint2(pk_bf16(s0 * r, s1 * r), pk_bf16(s2 * r, s3 * r));
  }
}

extern "C" void kernel_launch(void* const* d_in, const int* in_sizes, int n_in,
                              void* d_out, int out_size, void* d_ws, size_t ws_size,
                              hipStream_t stream) {
  const float* x  = (const float*)d_in[0];
  const float* wq = (const float*)d_in[1];
  const float* wk = (const float*)d_in[2];
  const float* wv = (const float*)d_in[3];
  const float* wo = (const float*)d_in[4];
  const float* w1 = (const float*)d_in[5];
  const float* w2 = (const float*)d_in[6];   // w2 before w3 in dict order
  const float* w3 = (const float*)d_in[7];
  const float* ga = (const float*)d_in[8];
  const float* gf = (const float*)d_in[9];
  float* out = (float*)d_out;

  char* p = (char*)d_ws;
  auto take = [&](size_t n) { char* r = p; p += (n + 255) & ~(size_t)255; return r; };
  u16* wqkvo_t = (u16*)take(4ull * 1024 * 1024 * 2);   // 4 x [1024][1024] bf16
  u16* w13_t   = (u16*)take(2ull * 2816 * 1024 * 2);   // w1^T then w3^T
  u16* w2_t    = (u16*)take(1024ull * 2816 * 2);
  u16* xn      = (u16*)take(4096ull * 1024 * 2);
  u16* qkvb    = (u16*)take(4096ull * 3072 * 2);
  u16* atn     = (u16*)take(4096ull * 1024 * 2);
  // union region: {Opart 16.8MB bf16 + ml 0.5MB} (attn passes) vs {hb, hn, ffb} (post-attn)
  char* uni    = take(48234496);
  u16* Opart   = (u16*)uni;                            // 1024 items x 8192 bf16
  float* mlb   = (float*)(uni + 1024ull * 8192 * 2);   // 1024 items x 128 f32
  float* hb    = (float*)uni;                          // 4096x1024 f32
  u16* hn      = (u16*)(uni + 4096ull * 1024 * 4);     // 4096x1024 bf16
  u16* ffb     = (u16*)(uni + 4096ull * 1024 * 6);     // 4096x2816 bf16

  u16* wqkv_t = wqkvo_t;
  u16* wo_t   = wqkvo_t + 3ull * 1024 * 1024;
  u16* w1_t   = w13_t;
  u16* w3_t   = w13_t + 2816ull * 1024;

  k_prep<<<12544, 256, 0, stream>>>(wq, wk, wv, wo, w1, w3, w2, wqkvo_t, w13_t, w2_t);

  k_rms<<<4096, 256, 0, stream>>>(x, ga, xn);
  k_gemm<0, 128><<<dim3(24, 32), 256, 0, stream>>>(xn, wqkv_t, qkvb, nullptr, nullptr, 4096, 3072, 1024);
  k_attn<<<1024, 512, 0, stream>>>(qkvb, Opart, mlb);
  k_amerge<<<512, 256, 0, stream>>>(Opart, mlb, atn);
  k_gemm<1, 64><<<dim3(16, 32), 256, 0, stream>>>(atn, wo_t, nullptr, hb, x, 4096, 1024, 1024);
  k_rms<<<4096, 256, 0, stream>>>(hb, gf, hn);
  k_ffn13<<<dim3(44, 32), 256, 0, stream>>>(hn, w1_t, w3_t, ffb, 4096, 2816, 1024);
  k_gemm<1, 64><<<dim3(16, 32), 256, 0, stream>>>(ffb, w2_t, nullptr, out, hb, 4096, 1024, 2816);
}